// Round 5
// baseline (107.006 us; speedup 1.0000x reference)
//
#include <hip/hip_runtime.h>
#include <hip/hip_bf16.h>

typedef unsigned short u16;
typedef __attribute__((ext_vector_type(8))) unsigned short ushort8;
typedef __attribute__((ext_vector_type(8))) __bf16 bf16x8;
typedef __attribute__((ext_vector_type(4))) float f32x4;

// N=16, L=4096, IN_DIM=32, D=E=512
#define NB 16
#define SEQ 4096
#define DIM 512
#define INDIM 32
#define NTOK (NB * SEQ)   // 65536

static __device__ __forceinline__ u16 f2bf(float f) {
    union { float f; unsigned u; } x; x.f = f;
    unsigned r = (x.u + 0x7FFFu + ((x.u >> 16) & 1u)) >> 16;
    return (u16)r;
}

__device__ __forceinline__ float dot32(const float* __restrict__ w, const float* v) {
    const float4* a = (const float4*)w;
    float acc = 0.f;
    #pragma unroll
    for (int i = 0; i < 8; ++i) {
        float4 p = a[i];
        acc += p.x * v[4*i] + p.y * v[4*i+1] + p.z * v[4*i+2] + p.w * v[4*i+3];
    }
    return acc;
}

// ===== prepA: wq2=wq@w_in, wk2=wk@w_in(bf16), wv2=wv@w_in; bq2=bq+wq@b_in etc =====
// Also zero-inits xu (512 f) and zd (16 f) — replaces pathological hipMemsetAsync fills.
__global__ __launch_bounds__(256) void k_prepA(const float* __restrict__ wq,
                                               const float* __restrict__ wk,
                                               const float* __restrict__ wv,
                                               const float* __restrict__ w_in,
                                               const float* __restrict__ b_in,
                                               const float* __restrict__ bq,
                                               const float* __restrict__ bk,
                                               float* __restrict__ wq2, float* __restrict__ bq2,
                                               u16* __restrict__ wk2b, float* __restrict__ bk2,
                                               float* __restrict__ wv2, float* __restrict__ bv2,
                                               float* __restrict__ xu, float* __restrict__ zd) {
    int bid = blockIdx.x;
    int tid = threadIdx.x;
    if (bid < 2) {
        int t = bid * 256 + tid;
        xu[t] = 0.f;           // 512 floats
        if (t < NB) zd[t] = 0.f;
    }
    int mat = bid >> 9;
    int e = bid & 511;
    int kc = tid >> 5, j = tid & 31;
    const float* A = (mat == 0 ? wq : (mat == 1 ? wk : wv)) + (long)e * DIM;
    float acc = 0.f, accb = 0.f;
    int d0 = kc * 64;
    #pragma unroll 8
    for (int i = 0; i < 64; ++i) {
        float a = A[d0 + i];
        acc += a * w_in[(d0 + i) * INDIM + j];
        accb += a * b_in[d0 + i];
    }
    __shared__ float sA[8][32];
    __shared__ float sB[8];
    sA[kc][j] = acc;
    if (j == 0) sB[kc] = accb;
    __syncthreads();
    if (tid < 32) {
        float s = 0.f;
        #pragma unroll
        for (int i = 0; i < 8; ++i) s += sA[i][tid];
        if (mat == 0) wq2[e * INDIM + tid] = s;
        else if (mat == 1) wk2b[e * INDIM + tid] = f2bf(s);
        else wv2[e * INDIM + tid] = s;
    } else if (tid == 32) {
        float s = 0.f;
        #pragma unroll
        for (int i = 0; i < 8; ++i) s += sB[i];
        if (mat == 0) bq2[e] = bq[e] + s;
        else if (mat == 1) bk2[e] = bk[e] + s;
        else bv2[e] = s;
    }
}

// ===== prepB: wo2=wo@wv2, wob=wo@(bv2+bv), bb=b_in+bo ; q0 ; wff2->bf16 =====
// grid 672: [0,512)=wo2 rows, [512,544)=q0, [544,672)=cvt
__global__ __launch_bounds__(256) void k_prepB(const float* __restrict__ wo,
                                               const float* __restrict__ wv2,
                                               const float* __restrict__ bv2,
                                               const float* __restrict__ bv,
                                               const float* __restrict__ b_in,
                                               const float* __restrict__ bo,
                                               const float* __restrict__ wq2,
                                               const float* __restrict__ bq2,
                                               const float* __restrict__ x,
                                               const float* __restrict__ wff2,
                                               float* __restrict__ wo2, float* __restrict__ wob,
                                               float* __restrict__ bb,
                                               float* __restrict__ q0, u16* __restrict__ wff2b) {
    int bid = blockIdx.x;
    int tid = threadIdx.x;
    if (bid < 512) {
        int e = bid;
        int kc = tid >> 5, j = tid & 31;
        const float* A = wo + (long)e * DIM;
        float acc = 0.f, accb = 0.f;
        int d0 = kc * 64;
        #pragma unroll 8
        for (int i = 0; i < 64; ++i) {
            int d = d0 + i;
            float a = A[d];
            acc += a * wv2[d * INDIM + j];
            accb += a * (bv2[d] + bv[d]);
        }
        __shared__ float sA[8][32];
        __shared__ float sB[8];
        sA[kc][j] = acc;
        if (j == 0) sB[kc] = accb;
        __syncthreads();
        if (tid < 32) {
            float s = 0.f;
            #pragma unroll
            for (int i = 0; i < 8; ++i) s += sA[i][tid];
            wo2[e * INDIM + tid] = s;
        } else if (tid == 32) {
            float s = 0.f;
            #pragma unroll
            for (int i = 0; i < 8; ++i) s += sB[i];
            wob[e] = s;
        } else if (tid == 33) {
            bb[e] = b_in[e] + bo[e];
        }
    } else if (bid < 544) {
        __shared__ float sx0[INDIM];
        int n = (bid - 512) >> 1;
        if (tid < INDIM) sx0[tid] = x[(long)n * SEQ * INDIM + tid];
        __syncthreads();
        int e = ((bid - 512) & 1) * 256 + tid;
        float acc = bq2[e] + dot32(wq2 + e * INDIM, sx0);
        q0[n * DIM + e] = (acc > 0.f) ? (acc + 1.f) : __expf(acc);
    } else {
        long i = ((long)(bid - 544) * 256 + tid) * 8;
        float4 a = *(const float4*)(wff2 + i);
        float4 b = *(const float4*)(wff2 + i + 4);
        u16 ob[8] = { f2bf(a.x), f2bf(a.y), f2bf(a.z), f2bf(a.w),
                      f2bf(b.x), f2bf(b.y), f2bf(b.z), f2bf(b.w) };
        *((ushort8*)(wff2b + i)) = *((ushort8*)ob);
    }
}

// ===== prepC: wf1x=wff1.G1.w_in, wf1u=wff1.G1.wo2 ; wf1w,wg1,wf1c,wb1 =====
// grid 1024: type = bid>>9, e = bid&511
__global__ __launch_bounds__(256) void k_prepC(const float* __restrict__ wff1,
                                               const float* __restrict__ w_in,
                                               const float* __restrict__ wo2,
                                               const float* __restrict__ g1,
                                               const float* __restrict__ b1,
                                               const float* __restrict__ wob,
                                               const float* __restrict__ bb,
                                               float* __restrict__ wf1x, float* __restrict__ wf1u,
                                               float* __restrict__ wf1w, float* __restrict__ wf1c,
                                               float* __restrict__ wg1, float* __restrict__ wb1) {
    int bid = blockIdx.x;
    int type = bid >> 9;
    int e = bid & 511;
    int tid = threadIdx.x;
    int kc = tid >> 5, j = tid & 31;
    const float* A = wff1 + (long)e * DIM;
    const float* B = (type == 0) ? w_in : wo2;
    float acc = 0.f, acc0 = 0.f, acc1 = 0.f;
    int d0 = kc * 64;
    #pragma unroll 4
    for (int i = 0; i < 64; ++i) {
        int d = d0 + i;
        float a = A[d];
        float g = g1[d];
        float ag = a * g;
        acc += ag * B[d * INDIM + j];
        if (type == 0) { acc0 += ag * wob[d]; acc1 += ag; }
        else           { acc0 += ag * bb[d];  acc1 += a * b1[d]; }
    }
    __shared__ float sA[8][32];
    __shared__ float s0[8], s1v[8];
    sA[kc][j] = acc;
    if (j == 0) { s0[kc] = acc0; s1v[kc] = acc1; }
    __syncthreads();
    if (tid < 32) {
        float s = 0.f;
        #pragma unroll
        for (int i = 0; i < 8; ++i) s += sA[i][tid];
        (type == 0 ? wf1x : wf1u)[e * INDIM + tid] = s;
    } else if (tid == 32) {
        float s = 0.f;
        #pragma unroll
        for (int i = 0; i < 8; ++i) s += s0[i];
        (type == 0 ? wf1w : wf1c)[e] = s;
    } else if (tid == 33) {
        float s = 0.f;
        #pragma unroll
        for (int i = 0; i < 8; ++i) s += s1v[i];
        (type == 0 ? wg1 : wb1)[e] = s;
    }
}

// ===== k_w: w_s = Kf_s . Q0 via MFMA over K=32 ; fold xu, zdot =====
#define WBM 128
__global__ __launch_bounds__(256) void k_w(const float* __restrict__ x,
                                           const u16* __restrict__ wk2b,
                                           const float* __restrict__ bk2,
                                           const float* __restrict__ q0,
                                           float* __restrict__ xu,
                                           float* __restrict__ zd) {
    __shared__ u16 sB[DIM * 40];
    __shared__ float sw[WBM];
    __shared__ float sxu[8][32];
    __shared__ float szz[8];
    int tid = threadIdx.x;
    int lane = tid & 63, wid = tid >> 6;
    long tbase = (long)blockIdx.x * WBM;
    int batch = (int)(tbase >> 12);

    #pragma unroll
    for (int p = 0; p < 8; ++p) {
        int f = (p * 256 + tid) * 8;
        int row = f >> 5, colc = f & 31;
        ushort8 v = *(const ushort8*)(wk2b + f);
        *(ushort8*)(sB + row * 40 + colc) = v;
    }

    int col = lane & 15;
    int koff = (lane >> 4) * 8;
    float q0v[32], bkv[32];
    #pragma unroll
    for (int ni = 0; ni < 32; ++ni) {
        q0v[ni] = q0[batch * DIM + ni * 16 + col];
        bkv[ni] = bk2[ni * 16 + col];
    }
    bf16x8 fa[2];
    #pragma unroll
    for (int mi = 0; mi < 2; ++mi) {
        const float* xr = x + (tbase + wid * 32 + mi * 16 + col) * INDIM + koff;
        float4 a0 = *(const float4*)(xr);
        float4 a1 = *(const float4*)(xr + 4);
        u16 tmp[8] = { f2bf(a0.x), f2bf(a0.y), f2bf(a0.z), f2bf(a0.w),
                       f2bf(a1.x), f2bf(a1.y), f2bf(a1.z), f2bf(a1.w) };
        fa[mi] = *(bf16x8*)tmp;
    }
    __syncthreads();

    f32x4 zero = {0.f, 0.f, 0.f, 0.f};
    float wpart[2][4] = {};
    #pragma unroll
    for (int nc = 0; nc < 4; ++nc) {
        bf16x8 fb[8];
        #pragma unroll
        for (int nj = 0; nj < 8; ++nj) {
            int row = (nc * 8 + nj) * 16 + col;
            fb[nj] = *(const bf16x8*)(sB + row * 40 + koff);
        }
        #pragma unroll
        for (int mi = 0; mi < 2; ++mi) {
            #pragma unroll
            for (int nj = 0; nj < 8; ++nj) {
                f32x4 acc = __builtin_amdgcn_mfma_f32_16x16x32_bf16(fa[mi], fb[nj], zero, 0, 0, 0);
                int ni = nc * 8 + nj;
                #pragma unroll
                for (int r = 0; r < 4; ++r) {
                    float v = acc[r] + bkv[ni];
                    v = (v > 0.f) ? (v + 1.f) : __expf(v);
                    wpart[mi][r] += v * q0v[ni];
                }
            }
        }
    }
    #pragma unroll
    for (int mi = 0; mi < 2; ++mi) {
        #pragma unroll
        for (int r = 0; r < 4; ++r) {
            float s = wpart[mi][r];
            s += __shfl_xor(s, 1, 64); s += __shfl_xor(s, 2, 64);
            s += __shfl_xor(s, 4, 64); s += __shfl_xor(s, 8, 64);
            if (col == 0) sw[wid * 32 + mi * 16 + (lane >> 4) * 4 + r] = s;
        }
    }
    __syncthreads();
    {
        int j = tid & 31, g = tid >> 5;
        float a = 0.f, z = 0.f;
        for (int tl = g; tl < WBM; tl += 8) {
            float wv = sw[tl];
            a += wv * x[(tbase + tl) * INDIM + j];
            if (j == 0) z += wv;
        }
        sxu[g][j] = a;
        if (j == 0) szz[g] = z;
    }
    __syncthreads();
    if (tid < 32) {
        float a = 0.f;
        #pragma unroll
        for (int g = 0; g < 8; ++g) a += sxu[g][tid];
        atomicAdd(&xu[batch * INDIM + tid], a);
    } else if (tid == 32) {
        float z = 0.f;
        #pragma unroll
        for (int g = 0; g < 8; ++g) z += szz[g];
        atomicAdd(&zd[batch], z);
    }
}

// ===== k_mid: per batch: r, LN1, r1, fpre, f (all 32-dots) =====
__device__ __forceinline__ void reduce2_512(float a, float b, int tid, float* lds16,
                                            float& oa, float& ob) {
    #pragma unroll
    for (int off = 1; off < 64; off <<= 1) {
        a += __shfl_xor(a, off, 64);
        b += __shfl_xor(b, off, 64);
    }
    int w = tid >> 6;
    if ((tid & 63) == 0) { lds16[w] = a; lds16[8 + w] = b; }
    __syncthreads();
    float ra = 0.f, rb = 0.f;
    #pragma unroll
    for (int i = 0; i < 8; ++i) { ra += lds16[i]; rb += lds16[8 + i]; }
    oa = ra; ob = rb;
    __syncthreads();
}

__global__ __launch_bounds__(512) void k_mid(const float* __restrict__ x,
                                             const float* __restrict__ w_in,
                                             const float* __restrict__ wo2,
                                             const float* __restrict__ wob,
                                             const float* __restrict__ bb,
                                             const float* __restrict__ wf1x,
                                             const float* __restrict__ wf1u,
                                             const float* __restrict__ wf1w,
                                             const float* __restrict__ wf1c,
                                             const float* __restrict__ wg1,
                                             const float* __restrict__ wb1,
                                             const float* __restrict__ g1,
                                             const float* __restrict__ b1,
                                             const float* __restrict__ bff1,
                                             const float* __restrict__ xu,
                                             const float* __restrict__ zdv,
                                             float* __restrict__ r1buf,
                                             u16* __restrict__ fbuf) {
    __shared__ float sx0[INDIM], sxu[INDIM];
    __shared__ float lds16[16];
    int n = blockIdx.x, tid = threadIdx.x;
    if (tid < INDIM) {
        sx0[tid] = x[(long)n * SEQ * INDIM + tid];
        sxu[tid] = xu[n * INDIM + tid];
    }
    __syncthreads();
    float zd = zdv[n];
    float Z = 1.f / (zd + 1e-6f);
    float zz = zd * Z;
    int d = tid;

    float rd = bb[d] + zz * wob[d] + dot32(w_in + d * INDIM, sx0)
             + Z * dot32(wo2 + d * INDIM, sxu);
    float sum, sumsq;
    reduce2_512(rd, rd * rd, tid, lds16, sum, sumsq);
    float mu1 = sum * (1.f / DIM);
    float s1 = rsqrtf(sumsq * (1.f / DIM) - mu1 * mu1 + 1e-5f);
    float r1d = (rd - mu1) * s1 * g1[d] + b1[d];
    r1buf[n * DIM + d] = r1d;

    float G = dot32(wf1x + d * INDIM, sx0) + Z * dot32(wf1u + d * INDIM, sxu)
            + zz * wf1w[d] + wf1c[d];
    float fp = s1 * (G - mu1 * wg1[d]) + wb1[d] + bff1[d];
    fbuf[n * DIM + d] = f2bf(fmaxf(fp, 0.f));
}

// ===== k_ytail: single block. y GEMM (MFMA) into LDS, then LN2/LNf/fc =====
__global__ __launch_bounds__(512) void k_ytail(const u16* __restrict__ fbuf,
                                               const u16* __restrict__ wff2b,
                                               const float* __restrict__ bff2,
                                               const float* __restrict__ r1buf,
                                               const float* __restrict__ g2,
                                               const float* __restrict__ b2,
                                               const float* __restrict__ gf,
                                               const float* __restrict__ bfv,
                                               const float* __restrict__ wfc,
                                               const float* __restrict__ bfc,
                                               float* __restrict__ out) {
    __shared__ float svbuf[NB][DIM];   // 32 KiB
    int tid = threadIdx.x;
    int lane = tid & 63, w = tid >> 6;  // 8 waves
    int cl = lane & 15, kh = lane >> 4;

    // y = r1 + wff2@f + bff2 : each wave does 4 tiles of 16 d-cols
    #pragma unroll
    for (int tile = 0; tile < 4; ++tile) {
        int dbase = tile * 128 + w * 16;
        f32x4 acc = {0.f, 0.f, 0.f, 0.f};
        const u16* arow = fbuf + cl * DIM + kh * 8;
        const u16* brow = wff2b + (long)(dbase + cl) * DIM + kh * 8;
        #pragma unroll
        for (int kc = 0; kc < 16; ++kc) {
            bf16x8 af = *(const bf16x8*)(arow + kc * 32);
            bf16x8 bf_ = *(const bf16x8*)(brow + kc * 32);
            acc = __builtin_amdgcn_mfma_f32_16x16x32_bf16(af, bf_, acc, 0, 0, 0);
        }
        int dcol = dbase + cl;
        float bfx = bff2[dcol];
        #pragma unroll
        for (int r = 0; r < 4; ++r) {
            int n = kh * 4 + r;
            svbuf[n][dcol] = acc[r] + bfx + r1buf[n * DIM + dcol];
        }
    }
    __syncthreads();

    // tail: each wave handles 2 batches
    #pragma unroll
    for (int rep = 0; rep < 2; ++rep) {
        int n = w * 2 + rep;
        int dbase = lane * 8;
        float v[8];
        {
            const float4* vp = (const float4*)(&svbuf[n][dbase]);
            float4 a = vp[0], b = vp[1];
            v[0] = a.x; v[1] = a.y; v[2] = a.z; v[3] = a.w;
            v[4] = b.x; v[5] = b.y; v[6] = b.z; v[7] = b.w;
        }
        float s = 0.f, ss = 0.f;
        #pragma unroll
        for (int i = 0; i < 8; ++i) { s += v[i]; ss += v[i] * v[i]; }
        #pragma unroll
        for (int off = 1; off < 64; off <<= 1) {
            s += __shfl_xor(s, off, 64);
            ss += __shfl_xor(ss, off, 64);
        }
        float mu = s * (1.f / DIM);
        float inv = rsqrtf(ss * (1.f / DIM) - mu * mu + 1e-5f);
        float h2[8];
        {
            const float4* gp = (const float4*)(g2 + dbase);
            const float4* bp = (const float4*)(b2 + dbase);
            float4 ga = gp[0], gb = gp[1], ba = bp[0], bb2 = bp[1];
            float gg[8] = { ga.x, ga.y, ga.z, ga.w, gb.x, gb.y, gb.z, gb.w };
            float bbx[8] = { ba.x, ba.y, ba.z, ba.w, bb2.x, bb2.y, bb2.z, bb2.w };
            #pragma unroll
            for (int i = 0; i < 8; ++i) h2[i] = (v[i] - mu) * inv * gg[i] + bbx[i];
        }
        s = 0.f; ss = 0.f;
        #pragma unroll
        for (int i = 0; i < 8; ++i) { s += h2[i]; ss += h2[i] * h2[i]; }
        #pragma unroll
        for (int off = 1; off < 64; off <<= 1) {
            s += __shfl_xor(s, off, 64);
            ss += __shfl_xor(ss, off, 64);
        }
        float mu2 = s * (1.f / DIM);
        float inv2 = rsqrtf(ss * (1.f / DIM) - mu2 * mu2 + 1e-5f);
        float p = 0.f;
        {
            const float4* gp = (const float4*)(gf + dbase);
            const float4* bp = (const float4*)(bfv + dbase);
            const float4* wp = (const float4*)(wfc + dbase);
            float4 ga = gp[0], gb = gp[1], ba = bp[0], bb2 = bp[1], wa = wp[0], wb = wp[1];
            float gg[8] = { ga.x, ga.y, ga.z, ga.w, gb.x, gb.y, gb.z, gb.w };
            float bbx[8] = { ba.x, ba.y, ba.z, ba.w, bb2.x, bb2.y, bb2.z, bb2.w };
            float ww[8] = { wa.x, wa.y, wa.z, wa.w, wb.x, wb.y, wb.z, wb.w };
            #pragma unroll
            for (int i = 0; i < 8; ++i)
                p += ww[i] * ((h2[i] - mu2) * inv2 * gg[i] + bbx[i]);
        }
        #pragma unroll
        for (int off = 1; off < 64; off <<= 1) p += __shfl_xor(p, off, 64);
        if (lane == 0) out[n] = p + bfc[0];
    }
}

extern "C" void kernel_launch(void* const* d_in, const int* in_sizes, int n_in,
                              void* d_out, int out_size, void* d_ws, size_t ws_size,
                              hipStream_t stream) {
    const float* x    = (const float*)d_in[0];
    const float* w_in = (const float*)d_in[1];
    const float* b_in = (const float*)d_in[2];
    const float* wq   = (const float*)d_in[3];
    const float* bq   = (const float*)d_in[4];
    const float* wk   = (const float*)d_in[5];
    const float* bk   = (const float*)d_in[6];
    const float* wv   = (const float*)d_in[7];
    const float* bv   = (const float*)d_in[8];
    const float* wo   = (const float*)d_in[9];
    const float* bo   = (const float*)d_in[10];
    const float* g1   = (const float*)d_in[11];
    const float* b1   = (const float*)d_in[12];
    const float* wff1 = (const float*)d_in[13];
    const float* bff1 = (const float*)d_in[14];
    const float* wff2 = (const float*)d_in[15];
    const float* bff2 = (const float*)d_in[16];
    const float* g2   = (const float*)d_in[17];
    const float* b2   = (const float*)d_in[18];
    const float* gf   = (const float*)d_in[19];
    const float* bf   = (const float*)d_in[20];
    const float* wfc  = (const float*)d_in[21];
    const float* bfc  = (const float*)d_in[22];

    char* ws = (char*)d_ws;
    float* wq2   = (float*)(ws + 0);         // 64 KiB
    float* bq2   = (float*)(ws + 65536);     // 2 KiB
    u16*   wk2b  = (u16*)  (ws + 67584);     // 32 KiB
    float* bk2   = (float*)(ws + 100352);    // 2 KiB
    float* wv2   = (float*)(ws + 102400);    // 64 KiB
    float* bv2   = (float*)(ws + 167936);    // 2 KiB
    float* wo2   = (float*)(ws + 169984);    // 64 KiB
    float* wob   = (float*)(ws + 235520);    // 2 KiB
    float* bb    = (float*)(ws + 237568);    // 2 KiB
    float* wf1x  = (float*)(ws + 239616);    // 64 KiB
    float* wf1u  = (float*)(ws + 305152);    // 64 KiB
    float* wf1w  = (float*)(ws + 370688);    // 2 KiB
    float* wf1c  = (float*)(ws + 372736);    // 2 KiB
    float* wg1   = (float*)(ws + 374784);    // 2 KiB
    float* wb1   = (float*)(ws + 376832);    // 2 KiB
    u16*   wff2b = (u16*)  (ws + 378880);    // 512 KiB
    float* q0    = (float*)(ws + 903168);    // 32 KiB
    float* xu    = (float*)(ws + 935936);    // 2 KiB
    float* zd    = (float*)(ws + 937984);    // 256 B
    u16*   fbuf  = (u16*)  (ws + 938240);    // 16 KiB
    float* r1buf = (float*)(ws + 954624);    // 32 KiB

    k_prepA<<<1536, 256, 0, stream>>>(wq, wk, wv, w_in, b_in, bq, bk,
                                      wq2, bq2, wk2b, bk2, wv2, bv2, xu, zd);
    k_prepB<<<672, 256, 0, stream>>>(wo, wv2, bv2, bv, b_in, bo, wq2, bq2, x, wff2,
                                     wo2, wob, bb, q0, wff2b);
    k_prepC<<<1024, 256, 0, stream>>>(wff1, w_in, wo2, g1, b1, wob, bb,
                                      wf1x, wf1u, wf1w, wf1c, wg1, wb1);
    k_w<<<NTOK / WBM, 256, 0, stream>>>(x, wk2b, bk2, q0, xu, zd);
    k_mid<<<NB, 512, 0, stream>>>(x, w_in, wo2, wob, bb, wf1x, wf1u, wf1w, wf1c,
                                  wg1, wb1, g1, b1, bff1, xu, zd, r1buf, fbuf);
    k_ytail<<<1, 512, 0, stream>>>(fbuf, wff2b, bff2, r1buf,
                                   g2, b2, gf, bf, wfc, bfc, (float*)d_out);
}

// Round 6
// 91.462 us; speedup vs baseline: 1.1700x; 1.1700x over previous
//
#include <hip/hip_runtime.h>
#include <hip/hip_bf16.h>

typedef unsigned short u16;
typedef __attribute__((ext_vector_type(8))) unsigned short ushort8;
typedef __attribute__((ext_vector_type(8))) __bf16 bf16x8;
typedef __attribute__((ext_vector_type(4))) float f32x4;

// N=16, L=4096, IN_DIM=32, D=E=512
#define NB 16
#define SEQ 4096
#define DIM 512
#define INDIM 32
#define NTOK (NB * SEQ)   // 65536

static __device__ __forceinline__ u16 f2bf(float f) {
    union { float f; unsigned u; } x; x.f = f;
    unsigned r = (x.u + 0x7FFFu + ((x.u >> 16) & 1u)) >> 16;
    return (u16)r;
}
static __device__ __forceinline__ float bf2f(u16 b) {
    union { unsigned u; float f; } x; x.u = ((unsigned)b) << 16;
    return x.f;
}

__device__ __forceinline__ float dot32(const float* __restrict__ w, const float* v) {
    const float4* a = (const float4*)w;
    float acc = 0.f;
    #pragma unroll
    for (int i = 0; i < 8; ++i) {
        float4 p = a[i];
        acc += p.x * v[4*i] + p.y * v[4*i+1] + p.z * v[4*i+2] + p.w * v[4*i+3];
    }
    return acc;
}

// ===================== k_p1: all stage-1 precomputes =====================
// grid 2432:
//   [0,1536): wq2/bq2 (mat0), wk2b/bk2 (mat1), wv2/wvb (mat2)   (+ xu/zd init on bid<2)
//   [1536,2048): wf1x, wf1c, wg1, wb1, bb  (e = bid-1536)
//   [2048,2304): wfo partials: wfop[kp] tile GEMM (wff1*g1)@wo, K-split 4
//   [2304,2432): wff2 -> bf16 cvt
__global__ __launch_bounds__(256) void k_p1(
    const float* __restrict__ wq, const float* __restrict__ wk, const float* __restrict__ wv,
    const float* __restrict__ wo, const float* __restrict__ w_in, const float* __restrict__ b_in,
    const float* __restrict__ bq, const float* __restrict__ bk, const float* __restrict__ bv,
    const float* __restrict__ bo, const float* __restrict__ g1, const float* __restrict__ b1,
    const float* __restrict__ wff1, const float* __restrict__ wff2,
    float* __restrict__ wq2, float* __restrict__ bq2,
    u16* __restrict__ wk2b, float* __restrict__ bk2,
    float* __restrict__ wv2, float* __restrict__ wvb,
    float* __restrict__ wf1x, float* __restrict__ wf1c,
    float* __restrict__ wg1, float* __restrict__ wb1, float* __restrict__ bb,
    float* __restrict__ wfop, u16* __restrict__ wff2b,
    float* __restrict__ xu, float* __restrict__ zd) {
    __shared__ float smem[32 * 65 + 32 * 64];   // 16.5 KiB, reused per segment
    int bid = blockIdx.x, tid = threadIdx.x;

    if (bid < 1536) {
        if (bid < 2) {
            int t = bid * 256 + tid;
            xu[t] = 0.f;
            if (t < NB) zd[t] = 0.f;
        }
        int mat = bid >> 9, e = bid & 511;
        int kc = tid >> 5, j = tid & 31;
        const float* A = (mat == 0 ? wq : (mat == 1 ? wk : wv)) + (long)e * DIM;
        float acc = 0.f, accb = 0.f;
        int d0 = kc * 64;
        #pragma unroll 8
        for (int i = 0; i < 64; ++i) {
            float a = A[d0 + i];
            acc  += a * w_in[(d0 + i) * INDIM + j];
            accb += a * b_in[d0 + i];
        }
        float* sA = smem;          // [8][32]
        float* sS = smem + 256;    // [8]
        sA[kc * 32 + j] = acc;
        if (j == 0) sS[kc] = accb;
        __syncthreads();
        if (tid < 32) {
            float s = 0.f;
            #pragma unroll
            for (int i = 0; i < 8; ++i) s += sA[i * 32 + tid];
            if (mat == 0) wq2[e * INDIM + tid] = s;
            else if (mat == 1) wk2b[e * INDIM + tid] = f2bf(s);
            else wv2[e * INDIM + tid] = s;
        } else if (tid == 32) {
            float s = 0.f;
            #pragma unroll
            for (int i = 0; i < 8; ++i) s += sS[i];
            if (mat == 0) bq2[e] = bq[e] + s;
            else if (mat == 1) bk2[e] = bk[e] + s;
            else wvb[e] = s + bv[e];
        }
    } else if (bid < 2048) {
        int e = bid - 1536;
        int kc = tid >> 5, j = tid & 31;
        const float* A = wff1 + (long)e * DIM;
        float accx = 0.f, accc = 0.f, accg = 0.f, accb1 = 0.f;
        int d0 = kc * 64;
        #pragma unroll 4
        for (int i = 0; i < 64; ++i) {
            int d = d0 + i;
            float a = A[d], g = g1[d], ag = a * g;
            accx  += ag * w_in[d * INDIM + j];
            accc  += ag * (b_in[d] + bo[d]);
            accg  += ag;
            accb1 += a * b1[d];
        }
        float* sA = smem;                 // [8][32]
        float* s0 = smem + 256;           // [8]
        float* s1p = smem + 264;          // [8]
        float* s2 = smem + 272;           // [8]
        sA[kc * 32 + j] = accx;
        if (j == 0) { s0[kc] = accc; s1p[kc] = accg; s2[kc] = accb1; }
        __syncthreads();
        if (tid < 32) {
            float s = 0.f;
            #pragma unroll
            for (int i = 0; i < 8; ++i) s += sA[i * 32 + tid];
            wf1x[e * INDIM + tid] = s;
        } else if (tid == 32) {
            float s = 0.f;
            #pragma unroll
            for (int i = 0; i < 8; ++i) s += s0[i];
            wf1c[e] = s;
        } else if (tid == 33) {
            float s = 0.f;
            #pragma unroll
            for (int i = 0; i < 8; ++i) s += s1p[i];
            wg1[e] = s;
        } else if (tid == 34) {
            float s = 0.f;
            #pragma unroll
            for (int i = 0; i < 8; ++i) s += s2[i];
            wb1[e] = s;
        } else if (tid == 35) {
            bb[e] = b_in[e] + bo[e];
        }
    } else if (bid < 2304) {
        // wfo partial: C[e0..+64][d0..+64] += (wff1*g1)[e][k] * wo[k][d], k in kp*128..+128
        int t = bid - 2048;
        int kp = t >> 6, et = (t >> 3) & 7, dt = t & 7;
        float* sA = smem;              // [32][65]
        float* sB = smem + 32 * 65;    // [32][64]
        int e0 = et * 64, d0 = dt * 64;
        float c[4][4] = {};
        for (int kc2 = 0; kc2 < 4; ++kc2) {
            int k0 = kp * 128 + kc2 * 32;
            {
                int e = tid >> 2, kg = (tid & 3) * 8;
                const float* src = wff1 + (long)(e0 + e) * DIM + k0 + kg;
                const float* gp = g1 + k0 + kg;
                #pragma unroll
                for (int q = 0; q < 8; ++q)
                    sA[(kg + q) * 65 + e] = src[q] * gp[q];
            }
            {
                int k = tid >> 3, dg = (tid & 7) * 8;
                const float* src = wo + (long)(k0 + k) * DIM + d0 + dg;
                float4 v0 = *(const float4*)src;
                float4 v1 = *(const float4*)(src + 4);
                float* dst = sB + k * 64 + dg;
                *(float4*)dst = v0;
                *(float4*)(dst + 4) = v1;
            }
            __syncthreads();
            int ty4 = (tid >> 4) * 4, tx4 = (tid & 15) * 4;
            #pragma unroll 8
            for (int k = 0; k < 32; ++k) {
                float a[4], b[4];
                #pragma unroll
                for (int i = 0; i < 4; ++i) a[i] = sA[k * 65 + ty4 + i];
                #pragma unroll
                for (int jv = 0; jv < 4; ++jv) b[jv] = sB[k * 64 + tx4 + jv];
                #pragma unroll
                for (int i = 0; i < 4; ++i)
                    #pragma unroll
                    for (int jv = 0; jv < 4; ++jv) c[i][jv] += a[i] * b[jv];
            }
            __syncthreads();
        }
        int ty4 = (tid >> 4) * 4, tx4 = (tid & 15) * 4;
        float* base = wfop + (long)kp * DIM * DIM + (long)(e0 + ty4) * DIM + d0 + tx4;
        #pragma unroll
        for (int i = 0; i < 4; ++i) {
            float4 v = { c[i][0], c[i][1], c[i][2], c[i][3] };
            *(float4*)(base + (long)i * DIM) = v;
        }
    } else {
        long i = ((long)(bid - 2304) * 256 + tid) * 8;
        float4 a = *(const float4*)(wff2 + i);
        float4 b = *(const float4*)(wff2 + i + 4);
        u16 ob[8] = { f2bf(a.x), f2bf(a.y), f2bf(a.z), f2bf(a.w),
                      f2bf(b.x), f2bf(b.y), f2bf(b.z), f2bf(b.w) };
        *((ushort8*)(wff2b + i)) = *((ushort8*)ob);
    }
}

// ===================== k_p2: stage-2 rows + q0 =====================
// grid 544: [0,512): per-row e: wo2, wob, wf1u, wf1w.  [512,544): q0.
__global__ __launch_bounds__(256) void k_p2(const float* __restrict__ wo,
                                            const float* __restrict__ wfop,
                                            const float* __restrict__ wv2,
                                            const float* __restrict__ wvb,
                                            const float* __restrict__ wq2,
                                            const float* __restrict__ bq2,
                                            const float* __restrict__ x,
                                            float* __restrict__ wo2, float* __restrict__ wob,
                                            float* __restrict__ wf1u, float* __restrict__ wf1w,
                                            float* __restrict__ q0) {
    __shared__ float sO[8][32];
    __shared__ float sU[8][32];
    __shared__ float sSb[8][2];
    __shared__ float sx0[INDIM];
    int bid = blockIdx.x, tid = threadIdx.x;
    if (bid < 512) {
        int e = bid;
        int kc = tid >> 5, j = tid & 31;
        const float* wor = wo + (long)e * DIM;
        const float* f0 = wfop + (long)e * DIM;
        float acco = 0.f, accu = 0.f, ao_b = 0.f, au_b = 0.f;
        int d0 = kc * 64;
        #pragma unroll 4
        for (int i = 0; i < 64; ++i) {
            int d = d0 + i;
            float a_o = wor[d];
            float a_f = f0[d] + f0[d + DIM * DIM] + f0[d + 2 * DIM * DIM] + f0[d + 3 * DIM * DIM];
            float wvj = wv2[d * INDIM + j];
            acco += a_o * wvj;
            accu += a_f * wvj;
            float wb = wvb[d];
            ao_b += a_o * wb;
            au_b += a_f * wb;
        }
        sO[kc][j] = acco;
        sU[kc][j] = accu;
        if (j == 0) { sSb[kc][0] = ao_b; sSb[kc][1] = au_b; }
        __syncthreads();
        if (tid < 32) {
            float s = 0.f;
            #pragma unroll
            for (int i = 0; i < 8; ++i) s += sO[i][tid];
            wo2[e * INDIM + tid] = s;
        } else if (tid < 64) {
            float s = 0.f;
            #pragma unroll
            for (int i = 0; i < 8; ++i) s += sU[i][tid - 32];
            wf1u[e * INDIM + (tid - 32)] = s;
        } else if (tid == 64) {
            float s = 0.f;
            #pragma unroll
            for (int i = 0; i < 8; ++i) s += sSb[i][0];
            wob[e] = s;
        } else if (tid == 65) {
            float s = 0.f;
            #pragma unroll
            for (int i = 0; i < 8; ++i) s += sSb[i][1];
            wf1w[e] = s;
        }
    } else {
        int n = (bid - 512) >> 1;
        if (tid < INDIM) sx0[tid] = x[(long)n * SEQ * INDIM + tid];
        __syncthreads();
        int e = ((bid - 512) & 1) * 256 + tid;
        float acc = bq2[e] + dot32(wq2 + e * INDIM, sx0);
        q0[n * DIM + e] = (acc > 0.f) ? (acc + 1.f) : __expf(acc);
    }
}

// ===== k_w: w_s = Kf_s . Q0 via MFMA over K=32 ; fold xu, zdot =====
#define WBM 128
__global__ __launch_bounds__(256) void k_w(const float* __restrict__ x,
                                           const u16* __restrict__ wk2b,
                                           const float* __restrict__ bk2,
                                           const float* __restrict__ q0,
                                           float* __restrict__ xu,
                                           float* __restrict__ zd) {
    __shared__ u16 sB[DIM * 40];
    __shared__ float sw[WBM];
    __shared__ float sxu[8][32];
    __shared__ float szz[8];
    int tid = threadIdx.x;
    int lane = tid & 63, wid = tid >> 6;
    long tbase = (long)blockIdx.x * WBM;
    int batch = (int)(tbase >> 12);

    #pragma unroll
    for (int p = 0; p < 8; ++p) {
        int f = (p * 256 + tid) * 8;
        int row = f >> 5, colc = f & 31;
        ushort8 v = *(const ushort8*)(wk2b + f);
        *(ushort8*)(sB + row * 40 + colc) = v;
    }

    int col = lane & 15;
    int koff = (lane >> 4) * 8;
    float q0v[32], bkv[32];
    #pragma unroll
    for (int ni = 0; ni < 32; ++ni) {
        q0v[ni] = q0[batch * DIM + ni * 16 + col];
        bkv[ni] = bk2[ni * 16 + col];
    }
    bf16x8 fa[2];
    #pragma unroll
    for (int mi = 0; mi < 2; ++mi) {
        const float* xr = x + (tbase + wid * 32 + mi * 16 + col) * INDIM + koff;
        float4 a0 = *(const float4*)(xr);
        float4 a1 = *(const float4*)(xr + 4);
        u16 tmp[8] = { f2bf(a0.x), f2bf(a0.y), f2bf(a0.z), f2bf(a0.w),
                       f2bf(a1.x), f2bf(a1.y), f2bf(a1.z), f2bf(a1.w) };
        fa[mi] = *(bf16x8*)tmp;
    }
    __syncthreads();

    f32x4 zero = {0.f, 0.f, 0.f, 0.f};
    float wpart[2][4] = {};
    #pragma unroll
    for (int nc = 0; nc < 4; ++nc) {
        bf16x8 fb[8];
        #pragma unroll
        for (int nj = 0; nj < 8; ++nj) {
            int row = (nc * 8 + nj) * 16 + col;
            fb[nj] = *(const bf16x8*)(sB + row * 40 + koff);
        }
        #pragma unroll
        for (int mi = 0; mi < 2; ++mi) {
            #pragma unroll
            for (int nj = 0; nj < 8; ++nj) {
                f32x4 acc = __builtin_amdgcn_mfma_f32_16x16x32_bf16(fa[mi], fb[nj], zero, 0, 0, 0);
                int ni = nc * 8 + nj;
                #pragma unroll
                for (int r = 0; r < 4; ++r) {
                    float v = acc[r] + bkv[ni];
                    v = (v > 0.f) ? (v + 1.f) : __expf(v);
                    wpart[mi][r] += v * q0v[ni];
                }
            }
        }
    }
    #pragma unroll
    for (int mi = 0; mi < 2; ++mi) {
        #pragma unroll
        for (int r = 0; r < 4; ++r) {
            float s = wpart[mi][r];
            s += __shfl_xor(s, 1, 64); s += __shfl_xor(s, 2, 64);
            s += __shfl_xor(s, 4, 64); s += __shfl_xor(s, 8, 64);
            if (col == 0) sw[wid * 32 + mi * 16 + (lane >> 4) * 4 + r] = s;
        }
    }
    __syncthreads();
    {
        int j = tid & 31, g = tid >> 5;
        float a = 0.f, z = 0.f;
        for (int tl = g; tl < WBM; tl += 8) {
            float wv = sw[tl];
            a += wv * x[(tbase + tl) * INDIM + j];
            if (j == 0) z += wv;
        }
        sxu[g][j] = a;
        if (j == 0) szz[g] = z;
    }
    __syncthreads();
    if (tid < 32) {
        float a = 0.f;
        #pragma unroll
        for (int g = 0; g < 8; ++g) a += sxu[g][tid];
        atomicAdd(&xu[batch * INDIM + tid], a);
    } else if (tid == 32) {
        float z = 0.f;
        #pragma unroll
        for (int g = 0; g < 8; ++g) z += szz[g];
        atomicAdd(&zd[batch], z);
    }
}

// ===================== k_final: per-batch mid + FF + tail =====================
__device__ __forceinline__ void reduce2_512(float a, float b, int tid, float* lds16,
                                            float& oa, float& ob) {
    #pragma unroll
    for (int off = 1; off < 64; off <<= 1) {
        a += __shfl_xor(a, off, 64);
        b += __shfl_xor(b, off, 64);
    }
    int w = tid >> 6;
    if ((tid & 63) == 0) { lds16[w] = a; lds16[8 + w] = b; }
    __syncthreads();
    float ra = 0.f, rb = 0.f;
    #pragma unroll
    for (int i = 0; i < 8; ++i) { ra += lds16[i]; rb += lds16[8 + i]; }
    oa = ra; ob = rb;
    __syncthreads();
}

__global__ __launch_bounds__(512) void k_final(
    const float* __restrict__ x, const float* __restrict__ w_in,
    const float* __restrict__ wo2, const float* __restrict__ wob,
    const float* __restrict__ bb,
    const float* __restrict__ wf1x, const float* __restrict__ wf1u,
    const float* __restrict__ wf1w, const float* __restrict__ wf1c,
    const float* __restrict__ wg1, const float* __restrict__ wb1,
    const float* __restrict__ g1, const float* __restrict__ b1,
    const float* __restrict__ bff1, const float* __restrict__ bff2,
    const u16* __restrict__ wff2b,
    const float* __restrict__ g2, const float* __restrict__ b2,
    const float* __restrict__ gf, const float* __restrict__ bfv,
    const float* __restrict__ wfc, const float* __restrict__ bfc,
    const float* __restrict__ xu, const float* __restrict__ zdv,
    float* __restrict__ out) {
    __shared__ float sx0[INDIM], sxu[INDIM];
    __shared__ float sf[DIM];
    __shared__ float lds16[16];
    int n = blockIdx.x, tid = threadIdx.x, d = tid;
    if (tid < INDIM) {
        sx0[tid] = x[(long)n * SEQ * INDIM + tid];
        sxu[tid] = xu[n * INDIM + tid];
    }
    __syncthreads();
    float zd = zdv[n];
    float Z = 1.f / (zd + 1e-6f);
    float zz = zd * Z;

    float rd = bb[d] + zz * wob[d] + dot32(w_in + d * INDIM, sx0)
             + Z * dot32(wo2 + d * INDIM, sxu);
    float sum, sumsq;
    reduce2_512(rd, rd * rd, tid, lds16, sum, sumsq);
    float mu1 = sum * (1.f / DIM);
    float s1 = rsqrtf(sumsq * (1.f / DIM) - mu1 * mu1 + 1e-5f);
    float r1 = (rd - mu1) * s1 * g1[d] + b1[d];

    float G = dot32(wf1x + d * INDIM, sx0) + Z * dot32(wf1u + d * INDIM, sxu)
            + zz * wf1w[d] + wf1c[d];
    float fp = s1 * (G - mu1 * wg1[d]) + wb1[d] + bff1[d];
    sf[d] = fmaxf(fp, 0.f);
    __syncthreads();

    // y = r1 + wff2 @ f + bff2   (bf16 weights, f32 f in LDS broadcast)
    float acc = 0.f;
    const u16* wr = wff2b + (long)d * DIM;
    for (int k = 0; k < DIM; k += 8) {
        ushort8 wv8 = *(const ushort8*)(wr + k);
        #pragma unroll
        for (int jj = 0; jj < 8; ++jj) acc += bf2f(wv8[jj]) * sf[k + jj];
    }
    float y = r1 + bff2[d] + acc;

    reduce2_512(y, y * y, tid, lds16, sum, sumsq);
    float mu2 = sum * (1.f / DIM);
    float inv2 = rsqrtf(sumsq * (1.f / DIM) - mu2 * mu2 + 1e-5f);
    float h2 = (y - mu2) * inv2 * g2[d] + b2[d];

    reduce2_512(h2, h2 * h2, tid, lds16, sum, sumsq);
    float mu3 = sum * (1.f / DIM);
    float inv3 = rsqrtf(sumsq * (1.f / DIM) - mu3 * mu3 + 1e-5f);
    float h3 = (h2 - mu3) * inv3 * gf[d] + bfv[d];

    float p = wfc[d] * h3;
    float dummy;
    reduce2_512(p, 0.f, tid, lds16, sum, dummy);
    if (tid == 0) out[n] = sum + bfc[0];
}

extern "C" void kernel_launch(void* const* d_in, const int* in_sizes, int n_in,
                              void* d_out, int out_size, void* d_ws, size_t ws_size,
                              hipStream_t stream) {
    const float* x    = (const float*)d_in[0];
    const float* w_in = (const float*)d_in[1];
    const float* b_in = (const float*)d_in[2];
    const float* wq   = (const float*)d_in[3];
    const float* bq   = (const float*)d_in[4];
    const float* wk   = (const float*)d_in[5];
    const float* bk   = (const float*)d_in[6];
    const float* wv   = (const float*)d_in[7];
    const float* bv   = (const float*)d_in[8];
    const float* wo   = (const float*)d_in[9];
    const float* bo   = (const float*)d_in[10];
    const float* g1   = (const float*)d_in[11];
    const float* b1   = (const float*)d_in[12];
    const float* wff1 = (const float*)d_in[13];
    const float* bff1 = (const float*)d_in[14];
    const float* wff2 = (const float*)d_in[15];
    const float* bff2 = (const float*)d_in[16];
    const float* g2   = (const float*)d_in[17];
    const float* b2   = (const float*)d_in[18];
    const float* gf   = (const float*)d_in[19];
    const float* bf   = (const float*)d_in[20];
    const float* wfc  = (const float*)d_in[21];
    const float* bfc  = (const float*)d_in[22];

    char* ws = (char*)d_ws;
    float* wq2   = (float*)(ws + 0);         // 64 KiB
    float* bq2   = (float*)(ws + 65536);     // 2 KiB
    u16*   wk2b  = (u16*)  (ws + 67584);     // 32 KiB
    float* bk2   = (float*)(ws + 100352);    // 2 KiB
    float* wv2   = (float*)(ws + 102400);    // 64 KiB
    float* wvb   = (float*)(ws + 167936);    // 2 KiB
    float* wo2   = (float*)(ws + 169984);    // 64 KiB
    float* wob   = (float*)(ws + 235520);    // 2 KiB
    float* bb    = (float*)(ws + 237568);    // 2 KiB
    float* wf1x  = (float*)(ws + 239616);    // 64 KiB
    float* wf1u  = (float*)(ws + 305152);    // 64 KiB
    float* wf1w  = (float*)(ws + 370688);    // 2 KiB
    float* wf1c  = (float*)(ws + 372736);    // 2 KiB
    float* wg1   = (float*)(ws + 374784);    // 2 KiB
    float* wb1   = (float*)(ws + 376832);    // 2 KiB
    u16*   wff2b = (u16*)  (ws + 378880);    // 512 KiB
    float* q0    = (float*)(ws + 903168);    // 32 KiB
    float* xu    = (float*)(ws + 935936);    // 2 KiB
    float* zd    = (float*)(ws + 937984);    // 256 B
    float* wfop  = (float*)(ws + 938240);    // 4 MiB : wfo partials [4][512][512]

    k_p1<<<2432, 256, 0, stream>>>(wq, wk, wv, wo, w_in, b_in, bq, bk, bv, bo,
                                   g1, b1, wff1, wff2,
                                   wq2, bq2, wk2b, bk2, wv2, wvb,
                                   wf1x, wf1c, wg1, wb1, bb, wfop, wff2b, xu, zd);
    k_p2<<<544, 256, 0, stream>>>(wo, wfop, wv2, wvb, wq2, bq2, x,
                                  wo2, wob, wf1u, wf1w, q0);
    k_w<<<NTOK / WBM, 256, 0, stream>>>(x, wk2b, bk2, q0, xu, zd);
    k_final<<<NB, 512, 0, stream>>>(x, w_in, wo2, wob, bb, wf1x, wf1u, wf1w, wf1c,
                                    wg1, wb1, g1, b1, bff1, bff2, wff2b,
                                    g2, b2, gf, bf, wfc, bfc, xu, zd, (float*)d_out);
}

// Round 7
// 81.242 us; speedup vs baseline: 1.3171x; 1.1258x over previous
//
#include <hip/hip_runtime.h>
#include <hip/hip_bf16.h>

typedef unsigned short u16;
typedef __attribute__((ext_vector_type(8))) unsigned short ushort8;
typedef __attribute__((ext_vector_type(8))) __bf16 bf16x8;
typedef __attribute__((ext_vector_type(4))) float f32x4;

// N=16, L=4096, IN_DIM=32, D=E=512
#define NB 16
#define SEQ 4096
#define DIM 512
#define INDIM 32
#define NTOK (NB * SEQ)   // 65536
#define WBM 128           // tokens per k_w tile
#define NTILE (NTOK / WBM) // 512

static __device__ __forceinline__ u16 f2bf(float f) {
    union { float f; unsigned u; } x; x.f = f;
    unsigned r = (x.u + 0x7FFFu + ((x.u >> 16) & 1u)) >> 16;
    return (u16)r;
}
static __device__ __forceinline__ float bf2f(u16 b) {
    union { unsigned u; float f; } x; x.u = ((unsigned)b) << 16;
    return x.f;
}

__device__ __forceinline__ float dot32(const float* __restrict__ w, const float* v) {
    const float4* a = (const float4*)w;
    float acc = 0.f;
    #pragma unroll
    for (int i = 0; i < 8; ++i) {
        float4 p = a[i];
        acc += p.x * v[4*i] + p.y * v[4*i+1] + p.z * v[4*i+2] + p.w * v[4*i+3];
    }
    return acc;
}

// ===================== k_p1: all input-only precomputes =====================
// grid 2368:
//   [0,1536): wq2/bq2 (mat0), wk2b/bk2 (mat1), wv2/wvb (mat2)
//   [1536,2048): wf1x, wf1c, wg1, wb1, bb  (e = bid-1536)
//   [2048,2304): wfop partials: (wff1*g1)@wo tile GEMM, K-split 4
//   [2304,2368): wff2 -> bf16 TRANSPOSED (wff2T[k][e]) via 64x64 LDS tiles
__global__ __launch_bounds__(256) void k_p1(
    const float* __restrict__ wq, const float* __restrict__ wk, const float* __restrict__ wv,
    const float* __restrict__ wo, const float* __restrict__ w_in, const float* __restrict__ b_in,
    const float* __restrict__ bq, const float* __restrict__ bk, const float* __restrict__ bv,
    const float* __restrict__ bo, const float* __restrict__ g1, const float* __restrict__ b1,
    const float* __restrict__ wff1, const float* __restrict__ wff2,
    float* __restrict__ wq2, float* __restrict__ bq2,
    u16* __restrict__ wk2b, float* __restrict__ bk2,
    float* __restrict__ wv2, float* __restrict__ wvb,
    float* __restrict__ wf1x, float* __restrict__ wf1c,
    float* __restrict__ wg1, float* __restrict__ wb1, float* __restrict__ bb,
    float* __restrict__ wfop, u16* __restrict__ wff2T) {
    __shared__ float smem[32 * 65 + 32 * 64];   // 16.6 KiB, reused per segment
    int bid = blockIdx.x, tid = threadIdx.x;

    if (bid < 1536) {
        int mat = bid >> 9, e = bid & 511;
        int kc = tid >> 5, j = tid & 31;
        const float* A = (mat == 0 ? wq : (mat == 1 ? wk : wv)) + (long)e * DIM;
        float acc = 0.f, accb = 0.f;
        int d0 = kc * 64;
        #pragma unroll 8
        for (int i = 0; i < 64; ++i) {
            float a = A[d0 + i];
            acc  += a * w_in[(d0 + i) * INDIM + j];
            accb += a * b_in[d0 + i];
        }
        float* sA = smem;          // [8][32]
        float* sS = smem + 256;    // [8]
        sA[kc * 32 + j] = acc;
        if (j == 0) sS[kc] = accb;
        __syncthreads();
        if (tid < 32) {
            float s = 0.f;
            #pragma unroll
            for (int i = 0; i < 8; ++i) s += sA[i * 32 + tid];
            if (mat == 0) wq2[e * INDIM + tid] = s;
            else if (mat == 1) wk2b[e * INDIM + tid] = f2bf(s);
            else wv2[e * INDIM + tid] = s;
        } else if (tid == 32) {
            float s = 0.f;
            #pragma unroll
            for (int i = 0; i < 8; ++i) s += sS[i];
            if (mat == 0) bq2[e] = bq[e] + s;
            else if (mat == 1) bk2[e] = bk[e] + s;
            else wvb[e] = s + bv[e];
        }
    } else if (bid < 2048) {
        int e = bid - 1536;
        int kc = tid >> 5, j = tid & 31;
        const float* A = wff1 + (long)e * DIM;
        float accx = 0.f, accc = 0.f, accg = 0.f, accb1 = 0.f;
        int d0 = kc * 64;
        #pragma unroll 4
        for (int i = 0; i < 64; ++i) {
            int d = d0 + i;
            float a = A[d], g = g1[d], ag = a * g;
            accx  += ag * w_in[d * INDIM + j];
            accc  += ag * (b_in[d] + bo[d]);
            accg  += ag;
            accb1 += a * b1[d];
        }
        float* sA = smem;                 // [8][32]
        float* s0 = smem + 256;           // [8]
        float* s1p = smem + 264;          // [8]
        float* s2 = smem + 272;           // [8]
        sA[kc * 32 + j] = accx;
        if (j == 0) { s0[kc] = accc; s1p[kc] = accg; s2[kc] = accb1; }
        __syncthreads();
        if (tid < 32) {
            float s = 0.f;
            #pragma unroll
            for (int i = 0; i < 8; ++i) s += sA[i * 32 + tid];
            wf1x[e * INDIM + tid] = s;
        } else if (tid == 32) {
            float s = 0.f;
            #pragma unroll
            for (int i = 0; i < 8; ++i) s += s0[i];
            wf1c[e] = s;
        } else if (tid == 33) {
            float s = 0.f;
            #pragma unroll
            for (int i = 0; i < 8; ++i) s += s1p[i];
            wg1[e] = s;
        } else if (tid == 34) {
            float s = 0.f;
            #pragma unroll
            for (int i = 0; i < 8; ++i) s += s2[i];
            wb1[e] = s;
        } else if (tid == 35) {
            bb[e] = b_in[e] + bo[e];
        }
    } else if (bid < 2304) {
        // wfop partial: C[e0..+64][d0..+64] = sum_k (wff1*g1)[e][k]*wo[k][d], k in kp*128..+128
        int t = bid - 2048;
        int kp = t >> 6, et = (t >> 3) & 7, dt = t & 7;
        float* sA = smem;              // [32][65]
        float* sB = smem + 32 * 65;    // [32][64]
        int e0 = et * 64, d0 = dt * 64;
        float c[4][4] = {};
        for (int kc2 = 0; kc2 < 4; ++kc2) {
            int k0 = kp * 128 + kc2 * 32;
            {
                int e = tid >> 2, kg = (tid & 3) * 8;
                const float* src = wff1 + (long)(e0 + e) * DIM + k0 + kg;
                const float* gp = g1 + k0 + kg;
                #pragma unroll
                for (int q = 0; q < 8; ++q)
                    sA[(kg + q) * 65 + e] = src[q] * gp[q];
            }
            {
                int k = tid >> 3, dg = (tid & 7) * 8;
                const float* src = wo + (long)(k0 + k) * DIM + d0 + dg;
                float4 v0 = *(const float4*)src;
                float4 v1 = *(const float4*)(src + 4);
                float* dst = sB + k * 64 + dg;
                *(float4*)dst = v0;
                *(float4*)(dst + 4) = v1;
            }
            __syncthreads();
            int ty4 = (tid >> 4) * 4, tx4 = (tid & 15) * 4;
            #pragma unroll 8
            for (int k = 0; k < 32; ++k) {
                float a[4], b[4];
                #pragma unroll
                for (int i = 0; i < 4; ++i) a[i] = sA[k * 65 + ty4 + i];
                #pragma unroll
                for (int jv = 0; jv < 4; ++jv) b[jv] = sB[k * 64 + tx4 + jv];
                #pragma unroll
                for (int i = 0; i < 4; ++i)
                    #pragma unroll
                    for (int jv = 0; jv < 4; ++jv) c[i][jv] += a[i] * b[jv];
            }
            __syncthreads();
        }
        int ty4 = (tid >> 4) * 4, tx4 = (tid & 15) * 4;
        float* base = wfop + (long)kp * DIM * DIM + (long)(e0 + ty4) * DIM + d0 + tx4;
        #pragma unroll
        for (int i = 0; i < 4; ++i) {
            float4 v = { c[i][0], c[i][1], c[i][2], c[i][3] };
            *(float4*)(base + (long)i * DIM) = v;
        }
    } else {
        // transpose+cvt: wff2T[k][e] = bf16(wff2[e][k]); 64x64 tiles
        int t = bid - 2304;            // 0..63
        int r = t >> 3, c = t & 7;     // e-tile, k-tile
        float* tile = smem;            // [64][65]
        int rr = tid >> 2, cc = (tid & 3) * 16;
        const float* src = wff2 + (long)(r * 64 + rr) * DIM + c * 64 + cc;
        #pragma unroll
        for (int i = 0; i < 4; ++i) {
            float4 v = *(const float4*)(src + i * 4);
            tile[rr * 65 + cc + i * 4 + 0] = v.x;
            tile[rr * 65 + cc + i * 4 + 1] = v.y;
            tile[rr * 65 + cc + i * 4 + 2] = v.z;
            tile[rr * 65 + cc + i * 4 + 3] = v.w;
        }
        __syncthreads();
        int orr = tid >> 2, occ = (tid & 3) * 16;   // k-local, e-chunk
        u16 ob[16];
        #pragma unroll
        for (int i = 0; i < 16; ++i) ob[i] = f2bf(tile[(occ + i) * 65 + orr]);
        u16* dst = wff2T + (long)(c * 64 + orr) * DIM + r * 64 + occ;
        *(ushort8*)dst = *(ushort8*)ob;
        *(ushort8*)(dst + 8) = *(ushort8*)(ob + 8);
    }
}

// ===================== k_wp2: [0,512)=p2 rows ; [512,1024)=k_w tiles =====================
__global__ __launch_bounds__(256) void k_wp2(
    const float* __restrict__ x,
    const float* __restrict__ wo, const float* __restrict__ wfop,
    const float* __restrict__ wv2, const float* __restrict__ wvb,
    const float* __restrict__ wq2, const float* __restrict__ bq2,
    const u16* __restrict__ wk2b, const float* __restrict__ bk2,
    float* __restrict__ wo2, float* __restrict__ wob,
    float* __restrict__ wf1u, float* __restrict__ wf1w,
    float* __restrict__ xup, float* __restrict__ zdp) {
    __shared__ u16 sB[DIM * 40];       // 40960 B
    __shared__ float s_q0[DIM];        // 2048
    __shared__ float sw[WBM];          // 512
    __shared__ float sxu8[8][32];      // 1024
    __shared__ float szz[8];           // 32
    __shared__ float sx0[INDIM];       // 128
    int bid = blockIdx.x, tid = threadIdx.x;

    if (bid < 512) {
        // p2 row: wo2/wob, wf1u/wf1w for e=bid
        int e = bid;
        int kc = tid >> 5, j = tid & 31;
        const float* wor = wo + (long)e * DIM;
        const float* f0 = wfop + (long)e * DIM;
        float acco = 0.f, accu = 0.f, ao_b = 0.f, au_b = 0.f;
        int d0 = kc * 64;
        #pragma unroll 4
        for (int i = 0; i < 64; ++i) {
            int d = d0 + i;
            float a_o = wor[d];
            float a_f = f0[d] + f0[d + DIM * DIM] + f0[d + 2 * DIM * DIM] + f0[d + 3 * DIM * DIM];
            float wvj = wv2[d * INDIM + j];
            acco += a_o * wvj;
            accu += a_f * wvj;
            float wb = wvb[d];
            ao_b += a_o * wb;
            au_b += a_f * wb;
        }
        float* sO = (float*)sB;          // [8][32]
        float* sU = (float*)sB + 256;    // [8][32]
        float* sSb = (float*)sB + 512;   // [8][2]
        sO[kc * 32 + j] = acco;
        sU[kc * 32 + j] = accu;
        if (j == 0) { sSb[kc * 2] = ao_b; sSb[kc * 2 + 1] = au_b; }
        __syncthreads();
        if (tid < 32) {
            float s = 0.f;
            #pragma unroll
            for (int i = 0; i < 8; ++i) s += sO[i * 32 + tid];
            wo2[e * INDIM + tid] = s;
        } else if (tid < 64) {
            float s = 0.f;
            #pragma unroll
            for (int i = 0; i < 8; ++i) s += sU[i * 32 + (tid - 32)];
            wf1u[e * INDIM + (tid - 32)] = s;
        } else if (tid == 64) {
            float s = 0.f;
            #pragma unroll
            for (int i = 0; i < 8; ++i) s += sSb[i * 2];
            wob[e] = s;
        } else if (tid == 65) {
            float s = 0.f;
            #pragma unroll
            for (int i = 0; i < 8; ++i) s += sSb[i * 2 + 1];
            wf1w[e] = s;
        }
        return;
    }

    // ---- k_w tile ----
    int tt = bid - 512;                 // 0..511
    int lane = tid & 63, wid = tid >> 6;
    long tbase = (long)tt * WBM;
    int batch = (int)(tbase >> 12);

    // stage wk2b -> LDS (padded stride 40)
    #pragma unroll
    for (int p = 0; p < 8; ++p) {
        int f = (p * 256 + tid) * 8;
        int row = f >> 5, colc = f & 31;
        ushort8 v = *(const ushort8*)(wk2b + f);
        *(ushort8*)(sB + row * 40 + colc) = v;
    }
    // x0 then q0 (local per block)
    if (tid < INDIM) sx0[tid] = x[(long)batch * SEQ * INDIM + tid];
    __syncthreads();
    #pragma unroll
    for (int rep = 0; rep < 2; ++rep) {
        int e = tid + rep * 256;
        float a = bq2[e] + dot32(wq2 + e * INDIM, sx0);
        s_q0[e] = (a > 0.f) ? (a + 1.f) : __expf(a);
    }

    int col = lane & 15;
    int koff = (lane >> 4) * 8;
    // A fragments direct from global x
    bf16x8 fa[2];
    #pragma unroll
    for (int mi = 0; mi < 2; ++mi) {
        const float* xr = x + (tbase + wid * 32 + mi * 16 + col) * INDIM + koff;
        float4 a0 = *(const float4*)(xr);
        float4 a1 = *(const float4*)(xr + 4);
        u16 tmp[8] = { f2bf(a0.x), f2bf(a0.y), f2bf(a0.z), f2bf(a0.w),
                       f2bf(a1.x), f2bf(a1.y), f2bf(a1.z), f2bf(a1.w) };
        fa[mi] = *(bf16x8*)tmp;
    }
    __syncthreads();   // sB + s_q0 ready

    float q0v[32], bkv[32];
    #pragma unroll
    for (int ni = 0; ni < 32; ++ni) {
        q0v[ni] = s_q0[ni * 16 + col];
        bkv[ni] = bk2[ni * 16 + col];
    }

    f32x4 zero = {0.f, 0.f, 0.f, 0.f};
    float wpart[2][4] = {};
    #pragma unroll
    for (int nc = 0; nc < 4; ++nc) {
        bf16x8 fb[8];
        #pragma unroll
        for (int nj = 0; nj < 8; ++nj) {
            int row = (nc * 8 + nj) * 16 + col;
            fb[nj] = *(const bf16x8*)(sB + row * 40 + koff);
        }
        #pragma unroll
        for (int mi = 0; mi < 2; ++mi) {
            #pragma unroll
            for (int nj = 0; nj < 8; ++nj) {
                f32x4 acc = __builtin_amdgcn_mfma_f32_16x16x32_bf16(fa[mi], fb[nj], zero, 0, 0, 0);
                int ni = nc * 8 + nj;
                #pragma unroll
                for (int r = 0; r < 4; ++r) {
                    float v = acc[r] + bkv[ni];
                    v = (v > 0.f) ? (v + 1.f) : __expf(v);
                    wpart[mi][r] += v * q0v[ni];
                }
            }
        }
    }
    #pragma unroll
    for (int mi = 0; mi < 2; ++mi) {
        #pragma unroll
        for (int r = 0; r < 4; ++r) {
            float s = wpart[mi][r];
            s += __shfl_xor(s, 1, 64); s += __shfl_xor(s, 2, 64);
            s += __shfl_xor(s, 4, 64); s += __shfl_xor(s, 8, 64);
            if (col == 0) sw[wid * 32 + mi * 16 + (lane >> 4) * 4 + r] = s;
        }
    }
    __syncthreads();
    {
        int j = tid & 31, g = tid >> 5;
        float a = 0.f, z = 0.f;
        for (int tl = g; tl < WBM; tl += 8) {
            float wv_ = sw[tl];
            a += wv_ * x[(tbase + tl) * INDIM + j];
            if (j == 0) z += wv_;
        }
        sxu8[g][j] = a;
        if (j == 0) szz[g] = z;
    }
    __syncthreads();
    if (tid < 32) {
        float a = 0.f;
        #pragma unroll
        for (int g = 0; g < 8; ++g) a += sxu8[g][tid];
        xup[tt * INDIM + tid] = a;
    } else if (tid == 32) {
        float z = 0.f;
        #pragma unroll
        for (int g = 0; g < 8; ++g) z += szz[g];
        zdp[tt] = z;
    }
}

// ===================== k_final: per-batch mid + FF(y coalesced) + tail =====================
__device__ __forceinline__ void reduce2_512(float a, float b, int tid, float* lds16,
                                            float& oa, float& ob) {
    #pragma unroll
    for (int off = 1; off < 64; off <<= 1) {
        a += __shfl_xor(a, off, 64);
        b += __shfl_xor(b, off, 64);
    }
    int w = tid >> 6;
    if ((tid & 63) == 0) { lds16[w] = a; lds16[8 + w] = b; }
    __syncthreads();
    float ra = 0.f, rb = 0.f;
    #pragma unroll
    for (int i = 0; i < 8; ++i) { ra += lds16[i]; rb += lds16[8 + i]; }
    oa = ra; ob = rb;
    __syncthreads();
}

__global__ __launch_bounds__(512) void k_final(
    const float* __restrict__ x, const float* __restrict__ w_in,
    const float* __restrict__ wo2, const float* __restrict__ wob,
    const float* __restrict__ bb,
    const float* __restrict__ wf1x, const float* __restrict__ wf1u,
    const float* __restrict__ wf1w, const float* __restrict__ wf1c,
    const float* __restrict__ wg1, const float* __restrict__ wb1,
    const float* __restrict__ g1, const float* __restrict__ b1,
    const float* __restrict__ bff1, const float* __restrict__ bff2,
    const u16* __restrict__ wff2T,
    const float* __restrict__ g2, const float* __restrict__ b2,
    const float* __restrict__ gf, const float* __restrict__ bfv,
    const float* __restrict__ wfc, const float* __restrict__ bfc,
    const float* __restrict__ xup, const float* __restrict__ zdp,
    float* __restrict__ out) {
    __shared__ float sx0[INDIM], sxu[INDIM];
    __shared__ float sf[DIM];
    __shared__ float spart[8][DIM];   // 16 KiB
    __shared__ float lds16[16];
    __shared__ float szd;
    int n = blockIdx.x, tid = threadIdx.x, d = tid;
    if (tid < INDIM) {
        float a = 0.f;
        #pragma unroll 8
        for (int slot = 0; slot < 32; ++slot)
            a += xup[(n * 32 + slot) * INDIM + tid];
        sxu[tid] = a;
        sx0[tid] = x[(long)n * SEQ * INDIM + tid];
    } else if (tid == 32) {
        float z = 0.f;
        #pragma unroll 8
        for (int slot = 0; slot < 32; ++slot) z += zdp[n * 32 + slot];
        szd = z;
    }
    __syncthreads();
    float zd = szd;
    float Z = 1.f / (zd + 1e-6f);
    float zz = zd * Z;

    float rd = bb[d] + zz * wob[d] + dot32(w_in + d * INDIM, sx0)
             + Z * dot32(wo2 + d * INDIM, sxu);
    float sum, sumsq;
    reduce2_512(rd, rd * rd, tid, lds16, sum, sumsq);
    float mu1 = sum * (1.f / DIM);
    float s1 = rsqrtf(sumsq * (1.f / DIM) - mu1 * mu1 + 1e-5f);
    float r1 = (rd - mu1) * s1 * g1[d] + b1[d];

    float G = dot32(wf1x + d * INDIM, sx0) + Z * dot32(wf1u + d * INDIM, sxu)
            + zz * wf1w[d] + wf1c[d];
    float fp = s1 * (G - mu1 * wg1[d]) + wb1[d] + bff1[d];
    sf[d] = fmaxf(fp, 0.f);
    __syncthreads();

    // y = r1 + wff2 @ f + bff2 — coalesced over wff2T[k][d], 8-way k-split
    {
        int kc = tid >> 6, dg = tid & 63;
        float ps[8] = {};
        const u16* base = wff2T + (long)(kc * 64) * DIM + dg * 8;
        #pragma unroll 8
        for (int k8 = 0; k8 < 64; ++k8) {
            ushort8 w8 = *(const ushort8*)(base + (long)k8 * DIM);
            float fk = sf[kc * 64 + k8];
            #pragma unroll
            for (int j = 0; j < 8; ++j) ps[j] += bf2f(w8[j]) * fk;
        }
        #pragma unroll
        for (int j = 0; j < 8; ++j) spart[kc][dg * 8 + j] = ps[j];
    }
    __syncthreads();
    float acc = 0.f;
    #pragma unroll
    for (int i = 0; i < 8; ++i) acc += spart[i][d];
    float y = r1 + bff2[d] + acc;

    reduce2_512(y, y * y, tid, lds16, sum, sumsq);
    float mu2 = sum * (1.f / DIM);
    float inv2 = rsqrtf(sumsq * (1.f / DIM) - mu2 * mu2 + 1e-5f);
    float h2 = (y - mu2) * inv2 * g2[d] + b2[d];

    reduce2_512(h2, h2 * h2, tid, lds16, sum, sumsq);
    float mu3 = sum * (1.f / DIM);
    float inv3 = rsqrtf(sumsq * (1.f / DIM) - mu3 * mu3 + 1e-5f);
    float h3 = (h2 - mu3) * inv3 * gf[d] + bfv[d];

    float p = wfc[d] * h3;
    float dummy;
    reduce2_512(p, 0.f, tid, lds16, sum, dummy);
    if (tid == 0) out[n] = sum + bfc[0];
}

extern "C" void kernel_launch(void* const* d_in, const int* in_sizes, int n_in,
                              void* d_out, int out_size, void* d_ws, size_t ws_size,
                              hipStream_t stream) {
    const float* x    = (const float*)d_in[0];
    const float* w_in = (const float*)d_in[1];
    const float* b_in = (const float*)d_in[2];
    const float* wq   = (const float*)d_in[3];
    const float* bq   = (const float*)d_in[4];
    const float* wk   = (const float*)d_in[5];
    const float* bk   = (const float*)d_in[6];
    const float* wv   = (const float*)d_in[7];
    const float* bv   = (const float*)d_in[8];
    const float* wo   = (const float*)d_in[9];
    const float* bo   = (const float*)d_in[10];
    const float* g1   = (const float*)d_in[11];
    const float* b1   = (const float*)d_in[12];
    const float* wff1 = (const float*)d_in[13];
    const float* bff1 = (const float*)d_in[14];
    const float* wff2 = (const float*)d_in[15];
    const float* bff2 = (const float*)d_in[16];
    const float* g2   = (const float*)d_in[17];
    const float* b2   = (const float*)d_in[18];
    const float* gf   = (const float*)d_in[19];
    const float* bf   = (const float*)d_in[20];
    const float* wfc  = (const float*)d_in[21];
    const float* bfc  = (const float*)d_in[22];

    char* ws = (char*)d_ws;
    float* wq2   = (float*)(ws + 0);         // 64 KiB
    float* bq2   = (float*)(ws + 65536);     // 2 KiB
    u16*   wk2b  = (u16*)  (ws + 67584);     // 32 KiB
    float* bk2   = (float*)(ws + 100352);    // 2 KiB
    float* wv2   = (float*)(ws + 102400);    // 64 KiB
    float* wvb   = (float*)(ws + 167936);    // 2 KiB
    float* wo2   = (float*)(ws + 169984);    // 64 KiB
    float* wob   = (float*)(ws + 235520);    // 2 KiB
    float* bb    = (float*)(ws + 237568);    // 2 KiB
    float* wf1x  = (float*)(ws + 239616);    // 64 KiB
    float* wf1u  = (float*)(ws + 305152);    // 64 KiB
    float* wf1w  = (float*)(ws + 370688);    // 2 KiB
    float* wf1c  = (float*)(ws + 372736);    // 2 KiB
    float* wg1   = (float*)(ws + 374784);    // 2 KiB
    float* wb1   = (float*)(ws + 376832);    // 2 KiB
    u16*   wff2T = (u16*)  (ws + 378880);    // 512 KiB (transposed bf16)
    float* xup   = (float*)(ws + 903168);    // 64 KiB  [512][32]
    float* zdp   = (float*)(ws + 968704);    // 2 KiB   [512]
    float* wfop  = (float*)(ws + 970752);    // 4 MiB   [4][512][512]

    k_p1<<<2368, 256, 0, stream>>>(wq, wk, wv, wo, w_in, b_in, bq, bk, bv, bo,
                                   g1, b1, wff1, wff2,
                                   wq2, bq2, wk2b, bk2, wv2, wvb,
                                   wf1x, wf1c, wg1, wb1, bb, wfop, wff2T);
    k_wp2<<<512 + NTILE, 256, 0, stream>>>(x, wo, wfop, wv2, wvb, wq2, bq2,
                                           wk2b, bk2, wo2, wob, wf1u, wf1w, xup, zdp);
    k_final<<<NB, 512, 0, stream>>>(x, w_in, wo2, wob, bb, wf1x, wf1u, wf1w, wf1c,
                                    wg1, wb1, g1, b1, bff1, bff2, wff2T,
                                    g2, b2, gf, bf, wfc, bfc, xup, zdp, (float*)d_out);
}